// Round 1
// baseline (949.961 us; speedup 1.0000x reference)
//
#include <hip/hip_runtime.h>

#define NE 32
#define NG 8
#define NK 4
#define ND 2048
#define NH 1024
#define NHS 4096
#define CAPE 1024
#define NT 4096

typedef float f32x4 __attribute__((ext_vector_type(4)));
typedef short s16x8 __attribute__((ext_vector_type(8)));

__device__ __forceinline__ short f2bf(float f) {
    return __builtin_bit_cast(short, (__bf16)f);
}

// ---------------------------------------------------------------------------
// Kernel 1: gating. One wave per token. fp32 logits, sigmoid, grouped top-k.
// ---------------------------------------------------------------------------
__global__ __launch_bounds__(256) void gate_kernel(
    const float* __restrict__ X, const float* __restrict__ Gw,
    const float* __restrict__ bias,
    int* __restrict__ topk_idx, float* __restrict__ topk_w)
{
    const int lane = threadIdx.x & 63;
    const int t = blockIdx.x * 4 + (threadIdx.x >> 6);
    const float* x = X + (size_t)t * ND;

    float xr[32];
#pragma unroll
    for (int i = 0; i < 32; i++) xr[i] = x[lane + i * 64];

    float scores[32];
#pragma unroll
    for (int e = 0; e < 32; e++) {
        const float* w = Gw + (size_t)e * ND;
        float a = 0.f;
#pragma unroll
        for (int i = 0; i < 32; i++) a = fmaf(xr[i], w[lane + i * 64], a);
#pragma unroll
        for (int s = 32; s > 0; s >>= 1) a += __shfl_xor(a, s);
        scores[e] = 1.0f / (1.0f + expf(-a));   // all lanes hold full sum
    }

    // routing (computed redundantly on all lanes; uniform)
    float sc_c[32];
#pragma unroll
    for (int e = 0; e < 32; e++) sc_c[e] = scores[e] + bias[e];

    float gs[8];
#pragma unroll
    for (int g = 0; g < 8; g++) {
        float a = sc_c[4 * g], b = sc_c[4 * g + 1], c = sc_c[4 * g + 2], d = sc_c[4 * g + 3];
        float hi1 = fmaxf(a, b), lo1 = fminf(a, b);
        float hi2 = fmaxf(c, d), lo2 = fminf(c, d);
        float m1 = fmaxf(hi1, hi2);
        float m2 = fmaxf(fminf(hi1, hi2), fmaxf(lo1, lo2));
        gs[g] = m1 + m2;  // sum of top-2 in group
    }

    unsigned gsel = 0;
#pragma unroll
    for (int it = 0; it < 4; it++) {     // top-4 groups, ties -> lowest index
        int best = -1; float bv = -1e30f;
#pragma unroll
        for (int g = 0; g < 8; g++) {
            bool avail = !((gsel >> g) & 1);
            if (avail && gs[g] > bv) { bv = gs[g]; best = g; }
        }
        gsel |= 1u << best;
    }

    unsigned esel = 0;
    int idxs[4]; float wts[4];
#pragma unroll
    for (int it = 0; it < 4; it++) {     // top-4 experts of masked scores
        int best = -1; float bv = -1e30f, braw = 0.f;
#pragma unroll
        for (int e = 0; e < 32; e++) {
            float mv = ((gsel >> (e >> 2)) & 1) ? sc_c[e] : 0.0f;
            bool avail = !((esel >> e) & 1);
            if (avail && mv > bv) { bv = mv; best = e; braw = scores[e]; }
        }
        esel |= 1u << best;
        idxs[it] = best; wts[it] = braw;   // weights from RAW sigmoid scores
    }

    float s = wts[0] + wts[1] + wts[2] + wts[3] + 1e-20f;
    if (lane == 0) {
#pragma unroll
        for (int k = 0; k < 4; k++) {
            topk_idx[t * 4 + k] = idxs[k];
            topk_w[t * 4 + k] = wts[k] / s * 2.5f;
        }
    }
}

// ---------------------------------------------------------------------------
// Kernel 2a/2b: expert dispatch lists
// ---------------------------------------------------------------------------
__global__ void zero_cnt(int* cnt) {
    if (threadIdx.x < NE) cnt[threadIdx.x] = 0;
}

__global__ void dispatch_kernel(const int* __restrict__ topk_idx,
                                const float* __restrict__ topk_w,
                                int* __restrict__ cnt,
                                int* __restrict__ tok_list,
                                float* __restrict__ w_list)
{
    int i = blockIdx.x * 256 + threadIdx.x;   // 0..T*K-1
    int e = topk_idx[i];
    int t = i >> 2;
    int pos = atomicAdd(&cnt[e], 1);
    if (pos < CAPE) {
        tok_list[e * CAPE + pos] = t;
        w_list[e * CAPE + pos] = topk_w[i];
    }
}

// ---------------------------------------------------------------------------
// Kernel 3: the GEMM. 128x128 tile, BK=32, 4 waves (2x2), 16x16x32 bf16 MFMA.
// MODE 0: routed up   (A = gathered X f32,  W = up_w[e],   out = relu2 -> Hbuf bf16)
// MODE 1: routed down (A = Hbuf bf16,       W = down_w[e], out = atomicAdd w * y)
// MODE 2: shared up   (A = X f32,           W = shared_up, out = relu2 -> Sbuf bf16)
// MODE 3: shared down (A = Sbuf bf16,       W = shared_dn, out = plain write)
// ---------------------------------------------------------------------------
#define LDK 40   // LDS K-stride (bf16 elems): 80B rows -> 16B aligned, <=2-way bank alias

template <int MODE>
__global__ __launch_bounds__(256, 2) void moe_gemm(
    const float* __restrict__ Af, const short* __restrict__ Ah,
    const float* __restrict__ W,
    const int* __restrict__ cnt, const int* __restrict__ tok_list,
    const float* __restrict__ w_list,
    short* __restrict__ Hout, float* __restrict__ out)
{
    constexpr int N = (MODE == 0) ? NH : (MODE == 1) ? ND : (MODE == 2) ? NHS : ND;
    constexpr int K = (MODE == 0) ? ND : (MODE == 1) ? NH : (MODE == 2) ? ND : NHS;

    const int e = blockIdx.z;
    const int m0 = blockIdx.y * 128, n0 = blockIdx.x * 128;

    int mcnt = 0;
    if constexpr (MODE == 0 || MODE == 1) {
        mcnt = min(cnt[e], CAPE);
        if (m0 >= mcnt) return;
    }

    __shared__ short As[128 * LDK];
    __shared__ short Bs[128 * LDK];

    const int tid = threadIdx.x;
    const int lane = tid & 63;
    const int wave = tid >> 6;
    const int wr = wave >> 1, wc = wave & 1;

    const float* Wb = W;
    if constexpr (MODE == 0) Wb += (size_t)e * NH * ND;
    if constexpr (MODE == 1) Wb += (size_t)e * ND * NH;

    f32x4 acc[4][4] = {};

    for (int k0 = 0; k0 < K; k0 += 32) {
        __syncthreads();
        // ---- stage A tile (128 x 32) ----
        if constexpr (MODE == 0 || MODE == 2) {
#pragma unroll
            for (int p = 0; p < 4; p++) {
                int r = p * 32 + (tid >> 3);
                int c = (tid & 7) * 4;
                float4 v = make_float4(0.f, 0.f, 0.f, 0.f);
                if constexpr (MODE == 0) {
                    int gr = m0 + r;
                    if (gr < mcnt) {
                        int tok = tok_list[e * CAPE + gr];
                        v = *(const float4*)(Af + (size_t)tok * ND + k0 + c);
                    }
                } else {
                    v = *(const float4*)(Af + (size_t)(m0 + r) * ND + k0 + c);
                }
                short4 h;
                h.x = f2bf(v.x); h.y = f2bf(v.y); h.z = f2bf(v.z); h.w = f2bf(v.w);
                *(short4*)(&As[r * LDK + c]) = h;
            }
        } else {
#pragma unroll
            for (int p = 0; p < 2; p++) {
                int r = p * 64 + (tid >> 2);
                int c = (tid & 3) * 8;
                const short* src;
                if constexpr (MODE == 1)
                    src = Ah + ((size_t)e * CAPE + m0 + r) * NH + k0 + c;
                else
                    src = Ah + (size_t)(m0 + r) * NHS + k0 + c;
                int4 v = *(const int4*)src;
                *(int4*)(&As[r * LDK + c]) = v;
            }
        }
        // ---- stage B tile (128 x 32), always f32 weights ----
#pragma unroll
        for (int p = 0; p < 4; p++) {
            int r = p * 32 + (tid >> 3);
            int c = (tid & 7) * 4;
            float4 v = *(const float4*)(Wb + (size_t)(n0 + r) * K + k0 + c);
            short4 h;
            h.x = f2bf(v.x); h.y = f2bf(v.y); h.z = f2bf(v.z); h.w = f2bf(v.w);
            *(short4*)(&Bs[r * LDK + c]) = h;
        }
        __syncthreads();

        // ---- MFMA ----
        s16x8 af[4], bf[4];
#pragma unroll
        for (int i = 0; i < 4; i++) {
            af[i] = *(const s16x8*)(&As[(wr * 64 + i * 16 + (lane & 15)) * LDK + (lane >> 4) * 8]);
            bf[i] = *(const s16x8*)(&Bs[(wc * 64 + i * 16 + (lane & 15)) * LDK + (lane >> 4) * 8]);
        }
#pragma unroll
        for (int i = 0; i < 4; i++)
#pragma unroll
            for (int j = 0; j < 4; j++)
                acc[i][j] = __builtin_amdgcn_mfma_f32_16x16x32_bf16(af[i], bf[j], acc[i][j], 0, 0, 0);
    }

    // ---- epilogue ----  C mapping: col = lane&15, row = (lane>>4)*4 + reg
    const int r0 = (lane >> 4) * 4;
    const int cc = lane & 15;

    if constexpr (MODE == 0 || MODE == 2) {
#pragma unroll
        for (int i = 0; i < 4; i++)
#pragma unroll
            for (int j = 0; j < 4; j++)
#pragma unroll
                for (int v = 0; v < 4; v++) {
                    int row = wr * 64 + i * 16 + r0 + v;
                    int col = wc * 64 + j * 16 + cc;
                    float val = acc[i][j][v];
                    float r = fmaxf(val, 0.f);
                    val = r * r;
                    if constexpr (MODE == 0)
                        Hout[((size_t)e * CAPE + m0 + row) * NH + (n0 + col)] = f2bf(val);
                    else
                        Hout[(size_t)(m0 + row) * NHS + (n0 + col)] = f2bf(val);
                }
    } else if constexpr (MODE == 3) {
#pragma unroll
        for (int i = 0; i < 4; i++)
#pragma unroll
            for (int j = 0; j < 4; j++)
#pragma unroll
                for (int v = 0; v < 4; v++) {
                    int row = wr * 64 + i * 16 + r0 + v;
                    int col = wc * 64 + j * 16 + cc;
                    out[(size_t)(m0 + row) * ND + (n0 + col)] = acc[i][j][v];
                }
    } else {  // MODE 1: weighted atomic scatter-add per assignment row
#pragma unroll
        for (int i = 0; i < 4; i++)
#pragma unroll
            for (int v = 0; v < 4; v++) {
                int row = wr * 64 + i * 16 + r0 + v;
                int grow = m0 + row;
                if (grow < mcnt) {
                    int tok = tok_list[e * CAPE + grow];
                    float w = w_list[e * CAPE + grow];
#pragma unroll
                    for (int j = 0; j < 4; j++) {
                        int col = wc * 64 + j * 16 + cc;
                        atomicAdd(&out[(size_t)tok * ND + (n0 + col)], w * acc[i][j][v]);
                    }
                }
            }
    }
}

// ---------------------------------------------------------------------------
extern "C" void kernel_launch(void* const* d_in, const int* in_sizes, int n_in,
                              void* d_out, int out_size, void* d_ws, size_t ws_size,
                              hipStream_t stream) {
    const float* X     = (const float*)d_in[0];
    const float* Gw    = (const float*)d_in[1];
    const float* bias  = (const float*)d_in[2];
    const float* up_w  = (const float*)d_in[3];
    const float* dn_w  = (const float*)d_in[4];
    const float* sup   = (const float*)d_in[5];
    const float* sdn   = (const float*)d_in[6];
    float* out = (float*)d_out;

    char* ws = (char*)d_ws;
    size_t off = 0;
    auto alloc = [&](size_t bytes) -> void* {
        off = (off + 255) & ~(size_t)255;
        void* p = ws + off;
        off += bytes;
        return p;
    };
    int*   cnt      = (int*)  alloc(NE * 4);
    int*   topk_idx = (int*)  alloc((size_t)NT * NK * 4);
    float* topk_w   = (float*)alloc((size_t)NT * NK * 4);
    int*   tok_list = (int*)  alloc((size_t)NE * CAPE * 4);
    float* w_list   = (float*)alloc((size_t)NE * CAPE * 4);
    short* Hbuf     = (short*)alloc((size_t)NE * CAPE * NH * 2);   // 64 MB
    short* Sbuf     = (short*)alloc((size_t)NT * NHS * 2);         // 32 MB

    gate_kernel<<<dim3(NT / 4), dim3(256), 0, stream>>>(X, Gw, bias, topk_idx, topk_w);
    zero_cnt<<<dim3(1), dim3(64), 0, stream>>>(cnt);
    dispatch_kernel<<<dim3(NT * NK / 256), dim3(256), 0, stream>>>(topk_idx, topk_w, cnt, tok_list, w_list);

    // routed up: grid (N/128, CAP/128, E)
    moe_gemm<0><<<dim3(NH / 128, CAPE / 128, NE), dim3(256), 0, stream>>>(
        X, nullptr, up_w, cnt, tok_list, w_list, Hbuf, nullptr);
    // shared up: grid (HS/128, T/128)
    moe_gemm<2><<<dim3(NHS / 128, NT / 128, 1), dim3(256), 0, stream>>>(
        X, nullptr, sup, nullptr, nullptr, nullptr, Sbuf, nullptr);
    // shared down (plain write of out) MUST precede routed down (atomic add)
    moe_gemm<3><<<dim3(ND / 128, NT / 128, 1), dim3(256), 0, stream>>>(
        nullptr, Sbuf, sdn, nullptr, nullptr, nullptr, nullptr, out);
    // routed down: grid (D/128, CAP/128, E)
    moe_gemm<1><<<dim3(ND / 128, CAPE / 128, NE), dim3(256), 0, stream>>>(
        nullptr, Hbuf, dn_w, cnt, tok_list, w_list, nullptr, out);
}

// Round 2
// 839.527 us; speedup vs baseline: 1.1315x; 1.1315x over previous
//
#include <hip/hip_runtime.h>

#define NE 32
#define NG 8
#define NK 4
#define ND 2048
#define NH 1024
#define NHS 4096
#define CAPE 1024
#define NT 4096

typedef float f32x4 __attribute__((ext_vector_type(4)));
typedef short s16x8 __attribute__((ext_vector_type(8)));

__device__ __forceinline__ short f2bf(float f) {
    return __builtin_bit_cast(short, (__bf16)f);
}

__device__ __forceinline__ void gload_lds16(const void* g, void* l) {
    __builtin_amdgcn_global_load_lds(
        (const __attribute__((address_space(1))) void*)g,
        (__attribute__((address_space(3))) void*)l, 16, 0, 0);
}

// ---------------------------------------------------------------------------
// Kernel 1: gating. One wave per token. fp32 logits, sigmoid, grouped top-k.
// ---------------------------------------------------------------------------
__global__ __launch_bounds__(256) void gate_kernel(
    const float* __restrict__ X, const float* __restrict__ Gw,
    const float* __restrict__ bias,
    int* __restrict__ topk_idx, float* __restrict__ topk_w)
{
    const int lane = threadIdx.x & 63;
    const int t = blockIdx.x * 4 + (threadIdx.x >> 6);
    const float* x = X + (size_t)t * ND;

    float xr[32];
#pragma unroll
    for (int i = 0; i < 32; i++) xr[i] = x[lane + i * 64];

    float scores[32];
#pragma unroll
    for (int e = 0; e < 32; e++) {
        const float* w = Gw + (size_t)e * ND;
        float a = 0.f;
#pragma unroll
        for (int i = 0; i < 32; i++) a = fmaf(xr[i], w[lane + i * 64], a);
#pragma unroll
        for (int s = 32; s > 0; s >>= 1) a += __shfl_xor(a, s);
        scores[e] = 1.0f / (1.0f + expf(-a));
    }

    float sc_c[32];
#pragma unroll
    for (int e = 0; e < 32; e++) sc_c[e] = scores[e] + bias[e];

    float gs[8];
#pragma unroll
    for (int g = 0; g < 8; g++) {
        float a = sc_c[4 * g], b = sc_c[4 * g + 1], c = sc_c[4 * g + 2], d = sc_c[4 * g + 3];
        float hi1 = fmaxf(a, b), lo1 = fminf(a, b);
        float hi2 = fmaxf(c, d), lo2 = fminf(c, d);
        float m1 = fmaxf(hi1, hi2);
        float m2 = fmaxf(fminf(hi1, hi2), fmaxf(lo1, lo2));
        gs[g] = m1 + m2;
    }

    unsigned gsel = 0;
#pragma unroll
    for (int it = 0; it < 4; it++) {
        int best = -1; float bv = -1e30f;
#pragma unroll
        for (int g = 0; g < 8; g++) {
            bool avail = !((gsel >> g) & 1);
            if (avail && gs[g] > bv) { bv = gs[g]; best = g; }
        }
        gsel |= 1u << best;
    }

    unsigned esel = 0;
    int idxs[4]; float wts[4];
#pragma unroll
    for (int it = 0; it < 4; it++) {
        int best = -1; float bv = -1e30f, braw = 0.f;
#pragma unroll
        for (int e = 0; e < 32; e++) {
            float mv = ((gsel >> (e >> 2)) & 1) ? sc_c[e] : 0.0f;
            bool avail = !((esel >> e) & 1);
            if (avail && mv > bv) { bv = mv; best = e; braw = scores[e]; }
        }
        esel |= 1u << best;
        idxs[it] = best; wts[it] = braw;
    }

    float s = wts[0] + wts[1] + wts[2] + wts[3] + 1e-20f;
    if (lane == 0) {
#pragma unroll
        for (int k = 0; k < 4; k++) {
            topk_idx[t * 4 + k] = idxs[k];
            topk_w[t * 4 + k] = wts[k] / s * 2.5f;
        }
    }
}

// ---------------------------------------------------------------------------
__global__ void zero_cnt(int* cnt) {
    if (threadIdx.x < NE) cnt[threadIdx.x] = 0;
}

__global__ void dispatch_kernel(const int* __restrict__ topk_idx,
                                const float* __restrict__ topk_w,
                                int* __restrict__ cnt,
                                int* __restrict__ tok_list,
                                float* __restrict__ w_list)
{
    int i = blockIdx.x * 256 + threadIdx.x;
    int e = topk_idx[i];
    int t = i >> 2;
    int pos = atomicAdd(&cnt[e], 1);
    if (pos < CAPE) {
        tok_list[e * CAPE + pos] = t;
        w_list[e * CAPE + pos] = topk_w[i];
    }
}

// ---------------------------------------------------------------------------
// f32 -> bf16 bulk conversion (8 elems / thread / iter, grid-stride)
// ---------------------------------------------------------------------------
__global__ __launch_bounds__(256) void cvt_f2bf(const float* __restrict__ in,
                                                short* __restrict__ out, int n8)
{
    int i = blockIdx.x * 256 + threadIdx.x;
    int stride = gridDim.x * 256;
    for (; i < n8; i += stride) {
        const f32x4* p = (const f32x4*)(in + (size_t)i * 8);
        f32x4 a = p[0], b = p[1];
        s16x8 h;
        h[0] = f2bf(a[0]); h[1] = f2bf(a[1]); h[2] = f2bf(a[2]); h[3] = f2bf(a[3]);
        h[4] = f2bf(b[0]); h[5] = f2bf(b[1]); h[6] = f2bf(b[2]); h[7] = f2bf(b[3]);
        *(s16x8*)(out + (size_t)i * 8) = h;
    }
}

// ---------------------------------------------------------------------------
// FAST GEMM (m97 structure): 128x128 tile, BK=64, global_load_lds width-16,
// 4 waves (2x2), 16x16x32 bf16 MFMA. All operands bf16 [N][K] / [M][K].
// MODE 0: routed up   (A = Xbf gathered,  B = up_bf[e],  out = relu2 -> Hbuf)
// MODE 1: routed down (A = Hbuf[e],       B = dn_bf[e],  out = atomicAdd w*y)
// MODE 2: shared up   (A = Xbf,           B = sup_bf,    out = relu2 -> Sbuf)
// MODE 3: shared down (A = Sbuf,          B = sdn_bf,    out = plain write)
// ---------------------------------------------------------------------------
template <int MODE>
__global__ __launch_bounds__(256) void moe_gemm_bf(
    const short* __restrict__ Abase, const short* __restrict__ Bbase,
    const int* __restrict__ cnt, const int* __restrict__ tok_list,
    const float* __restrict__ w_list,
    short* __restrict__ Hout, float* __restrict__ out)
{
    constexpr int K = (MODE == 0) ? ND : (MODE == 1) ? NH : (MODE == 2) ? ND : NHS;

    const int e = blockIdx.z;
    const int m0 = blockIdx.y * 128, n0 = blockIdx.x * 128;

    int mcnt = 0;
    if constexpr (MODE == 0 || MODE == 1) {
        mcnt = min(cnt[e], CAPE);
        if (m0 >= mcnt) return;
    }

    __shared__ short As[128 * 64];
    __shared__ short Bs[128 * 64];

    const int tid = threadIdx.x;
    const int lane = tid & 63;
    const int wave = tid >> 6;
    const int wr = wave >> 1, wc = wave & 1;

    const short* Ab = Abase;
    const short* Bb = Bbase;
    if constexpr (MODE == 0) Bb += (size_t)e * NH * ND;
    if constexpr (MODE == 1) { Ab += (size_t)e * CAPE * NH; Bb += (size_t)e * ND * NH; }

    // per-thread staging sources (hoisted out of K-loop)
    const int rl = lane >> 3;         // row within 8-row chunk
    const int cl = (lane & 7) * 8;    // k element offset of this lane's 16B
    const short* asrc[4];
    const short* bsrc[4];
    short* adst[4];
    short* bdst[4];
#pragma unroll
    for (int i = 0; i < 4; i++) {
        int ci = i * 4 + wave;        // 1KB chunk index 0..15
        int r = ci * 8 + rl;          // tile row 0..127
        if constexpr (MODE == 0) {
            int gr = min(m0 + r, mcnt - 1);
            int tok = tok_list[e * CAPE + gr];
            asrc[i] = Abase + (size_t)tok * ND + cl;
        } else if constexpr (MODE == 1) {
            asrc[i] = Ab + (size_t)(m0 + r) * NH + cl;
        } else if constexpr (MODE == 2) {
            asrc[i] = Abase + (size_t)(m0 + r) * ND + cl;
        } else {
            asrc[i] = Abase + (size_t)(m0 + r) * NHS + cl;
        }
        bsrc[i] = Bb + (size_t)(n0 + r) * K + cl;
        adst[i] = &As[ci * 512];
        bdst[i] = &Bs[ci * 512];
    }

    f32x4 acc[4][4] = {};

    for (int k0 = 0; k0 < K; k0 += 64) {
        __syncthreads();                       // prev compute done
#pragma unroll
        for (int i = 0; i < 4; i++) {
            gload_lds16(asrc[i] + k0, adst[i]);
            gload_lds16(bsrc[i] + k0, bdst[i]);
        }
        __syncthreads();                       // vmcnt drained -> LDS ready

        s16x8 af[2][4], bfr[2][4];
#pragma unroll
        for (int kk = 0; kk < 2; kk++)
#pragma unroll
            for (int i = 0; i < 4; i++) {
                af[kk][i]  = *(const s16x8*)(&As[(wr * 64 + i * 16 + (lane & 15)) * 64 + kk * 32 + (lane >> 4) * 8]);
                bfr[kk][i] = *(const s16x8*)(&Bs[(wc * 64 + i * 16 + (lane & 15)) * 64 + kk * 32 + (lane >> 4) * 8]);
            }
#pragma unroll
        for (int i = 0; i < 4; i++)
#pragma unroll
            for (int j = 0; j < 4; j++) {
                acc[i][j] = __builtin_amdgcn_mfma_f32_16x16x32_bf16(af[0][i], bfr[0][j], acc[i][j], 0, 0, 0);
                acc[i][j] = __builtin_amdgcn_mfma_f32_16x16x32_bf16(af[1][i], bfr[1][j], acc[i][j], 0, 0, 0);
            }
    }

    // ---- epilogue ----  C mapping: col = lane&15, row = (lane>>4)*4 + reg
    const int r0 = (lane >> 4) * 4;
    const int cc = lane & 15;

    if constexpr (MODE == 0 || MODE == 2) {
#pragma unroll
        for (int i = 0; i < 4; i++)
#pragma unroll
            for (int j = 0; j < 4; j++)
#pragma unroll
                for (int v = 0; v < 4; v++) {
                    int row = wr * 64 + i * 16 + r0 + v;
                    int col = wc * 64 + j * 16 + cc;
                    float val = acc[i][j][v];
                    float r = fmaxf(val, 0.f);
                    val = r * r;
                    if constexpr (MODE == 0)
                        Hout[((size_t)e * CAPE + m0 + row) * NH + (n0 + col)] = f2bf(val);
                    else
                        Hout[(size_t)(m0 + row) * NHS + (n0 + col)] = f2bf(val);
                }
    } else if constexpr (MODE == 3) {
#pragma unroll
        for (int i = 0; i < 4; i++)
#pragma unroll
            for (int j = 0; j < 4; j++)
#pragma unroll
                for (int v = 0; v < 4; v++) {
                    int row = wr * 64 + i * 16 + r0 + v;
                    int col = wc * 64 + j * 16 + cc;
                    out[(size_t)(m0 + row) * ND + (n0 + col)] = acc[i][j][v];
                }
    } else {  // MODE 1: weighted atomic scatter-add
#pragma unroll
        for (int i = 0; i < 4; i++)
#pragma unroll
            for (int v = 0; v < 4; v++) {
                int row = wr * 64 + i * 16 + r0 + v;
                int grow = m0 + row;
                if (grow < mcnt) {
                    int tok = tok_list[e * CAPE + grow];
                    float w = w_list[e * CAPE + grow];
#pragma unroll
                    for (int j = 0; j < 4; j++) {
                        int col = wc * 64 + j * 16 + cc;
                        atomicAdd(&out[(size_t)tok * ND + (n0 + col)], w * acc[i][j][v]);
                    }
                }
            }
    }
}

// ---------------------------------------------------------------------------
// FALLBACK GEMM (round-1, fused f32->bf16 staging) — used if ws too small.
// ---------------------------------------------------------------------------
#define LDK 40

template <int MODE>
__global__ __launch_bounds__(256, 2) void moe_gemm_f32(
    const float* __restrict__ Af, const short* __restrict__ Ah,
    const float* __restrict__ W,
    const int* __restrict__ cnt, const int* __restrict__ tok_list,
    const float* __restrict__ w_list,
    short* __restrict__ Hout, float* __restrict__ out)
{
    constexpr int K = (MODE == 0) ? ND : (MODE == 1) ? NH : (MODE == 2) ? ND : NHS;

    const int e = blockIdx.z;
    const int m0 = blockIdx.y * 128, n0 = blockIdx.x * 128;

    int mcnt = 0;
    if constexpr (MODE == 0 || MODE == 1) {
        mcnt = min(cnt[e], CAPE);
        if (m0 >= mcnt) return;
    }

    __shared__ short As[128 * LDK];
    __shared__ short Bs[128 * LDK];

    const int tid = threadIdx.x;
    const int lane = tid & 63;
    const int wave = tid >> 6;
    const int wr = wave >> 1, wc = wave & 1;

    const float* Wb = W;
    if constexpr (MODE == 0) Wb += (size_t)e * NH * ND;
    if constexpr (MODE == 1) Wb += (size_t)e * ND * NH;

    f32x4 acc[4][4] = {};

    for (int k0 = 0; k0 < K; k0 += 32) {
        __syncthreads();
        if constexpr (MODE == 0 || MODE == 2) {
#pragma unroll
            for (int p = 0; p < 4; p++) {
                int r = p * 32 + (tid >> 3);
                int c = (tid & 7) * 4;
                float4 v = make_float4(0.f, 0.f, 0.f, 0.f);
                if constexpr (MODE == 0) {
                    int gr = m0 + r;
                    if (gr < mcnt) {
                        int tok = tok_list[e * CAPE + gr];
                        v = *(const float4*)(Af + (size_t)tok * ND + k0 + c);
                    }
                } else {
                    v = *(const float4*)(Af + (size_t)(m0 + r) * ND + k0 + c);
                }
                short4 h;
                h.x = f2bf(v.x); h.y = f2bf(v.y); h.z = f2bf(v.z); h.w = f2bf(v.w);
                *(short4*)(&As[r * LDK + c]) = h;
            }
        } else {
#pragma unroll
            for (int p = 0; p < 2; p++) {
                int r = p * 64 + (tid >> 2);
                int c = (tid & 3) * 8;
                const short* src;
                if constexpr (MODE == 1)
                    src = Ah + ((size_t)e * CAPE + m0 + r) * NH + k0 + c;
                else
                    src = Ah + (size_t)(m0 + r) * NHS + k0 + c;
                int4 v = *(const int4*)src;
                *(int4*)(&As[r * LDK + c]) = v;
            }
        }
#pragma unroll
        for (int p = 0; p < 4; p++) {
            int r = p * 32 + (tid >> 3);
            int c = (tid & 7) * 4;
            float4 v = *(const float4*)(Wb + (size_t)(n0 + r) * K + k0 + c);
            short4 h;
            h.x = f2bf(v.x); h.y = f2bf(v.y); h.z = f2bf(v.z); h.w = f2bf(v.w);
            *(short4*)(&Bs[r * LDK + c]) = h;
        }
        __syncthreads();

        s16x8 af[4], bfr[4];
#pragma unroll
        for (int i = 0; i < 4; i++) {
            af[i]  = *(const s16x8*)(&As[(wr * 64 + i * 16 + (lane & 15)) * LDK + (lane >> 4) * 8]);
            bfr[i] = *(const s16x8*)(&Bs[(wc * 64 + i * 16 + (lane & 15)) * LDK + (lane >> 4) * 8]);
        }
#pragma unroll
        for (int i = 0; i < 4; i++)
#pragma unroll
            for (int j = 0; j < 4; j++)
                acc[i][j] = __builtin_amdgcn_mfma_f32_16x16x32_bf16(af[i], bfr[j], acc[i][j], 0, 0, 0);
    }

    const int r0 = (lane >> 4) * 4;
    const int cc = lane & 15;

    if constexpr (MODE == 0 || MODE == 2) {
#pragma unroll
        for (int i = 0; i < 4; i++)
#pragma unroll
            for (int j = 0; j < 4; j++)
#pragma unroll
                for (int v = 0; v < 4; v++) {
                    int row = wr * 64 + i * 16 + r0 + v;
                    int col = wc * 64 + j * 16 + cc;
                    float val = acc[i][j][v];
                    float r = fmaxf(val, 0.f);
                    val = r * r;
                    if constexpr (MODE == 0)
                        Hout[((size_t)e * CAPE + m0 + row) * NH + (n0 + col)] = f2bf(val);
                    else
                        Hout[(size_t)(m0 + row) * NHS + (n0 + col)] = f2bf(val);
                }
    } else if constexpr (MODE == 3) {
#pragma unroll
        for (int i = 0; i < 4; i++)
#pragma unroll
            for (int j = 0; j < 4; j++)
#pragma unroll
                for (int v = 0; v < 4; v++) {
                    int row = wr * 64 + i * 16 + r0 + v;
                    int col = wc * 64 + j * 16 + cc;
                    out[(size_t)(m0 + row) * ND + (n0 + col)] = acc[i][j][v];
                }
    } else {
#pragma unroll
        for (int i = 0; i < 4; i++)
#pragma unroll
            for (int v = 0; v < 4; v++) {
                int row = wr * 64 + i * 16 + r0 + v;
                int grow = m0 + row;
                if (grow < mcnt) {
                    int tok = tok_list[e * CAPE + grow];
                    float w = w_list[e * CAPE + grow];
#pragma unroll
                    for (int j = 0; j < 4; j++) {
                        int col = wc * 64 + j * 16 + cc;
                        atomicAdd(&out[(size_t)tok * ND + (n0 + col)], w * acc[i][j][v]);
                    }
                }
            }
    }
}

// ---------------------------------------------------------------------------
extern "C" void kernel_launch(void* const* d_in, const int* in_sizes, int n_in,
                              void* d_out, int out_size, void* d_ws, size_t ws_size,
                              hipStream_t stream) {
    const float* X    = (const float*)d_in[0];
    const float* Gw   = (const float*)d_in[1];
    const float* bias = (const float*)d_in[2];
    const float* up_w = (const float*)d_in[3];
    const float* dn_w = (const float*)d_in[4];
    const float* sup  = (const float*)d_in[5];
    const float* sdn  = (const float*)d_in[6];
    float* out = (float*)d_out;

    char* ws = (char*)d_ws;
    size_t off = 0;
    auto alloc = [&](size_t bytes) -> void* {
        off = (off + 255) & ~(size_t)255;
        void* p = ws + off;
        off += bytes;
        return p;
    };
    int*   cnt      = (int*)  alloc(NE * 4);
    int*   topk_idx = (int*)  alloc((size_t)NT * NK * 4);
    float* topk_w   = (float*)alloc((size_t)NT * NK * 4);
    int*   tok_list = (int*)  alloc((size_t)NE * CAPE * 4);
    float* w_list   = (float*)alloc((size_t)NE * CAPE * 4);
    short* Hbuf     = (short*)alloc((size_t)NE * CAPE * NH * 2);   // 64 MB
    short* Sbuf     = (short*)alloc((size_t)NT * NHS * 2);         // 32 MB
    size_t slow_need = off;
    short* Xbf      = (short*)alloc((size_t)NT * ND * 2);          // 16 MB
    short* up_bf    = (short*)alloc((size_t)NE * NH * ND * 2);     // 128 MB
    short* dn_bf    = (short*)alloc((size_t)NE * ND * NH * 2);     // 128 MB
    short* sup_bf   = (short*)alloc((size_t)NHS * ND * 2);         // 16 MB
    short* sdn_bf   = (short*)alloc((size_t)ND * NHS * 2);         // 16 MB
    size_t fast_need = off;
    (void)slow_need;

    gate_kernel<<<dim3(NT / 4), dim3(256), 0, stream>>>(X, Gw, bias, topk_idx, topk_w);
    zero_cnt<<<dim3(1), dim3(64), 0, stream>>>(cnt);
    dispatch_kernel<<<dim3(NT * NK / 256), dim3(256), 0, stream>>>(topk_idx, topk_w, cnt, tok_list, w_list);

    if (ws_size >= fast_need) {
        // bulk f32 -> bf16 conversion
        cvt_f2bf<<<dim3(1024), dim3(256), 0, stream>>>(X,    Xbf,    NT * ND / 8);
        cvt_f2bf<<<dim3(2048), dim3(256), 0, stream>>>(up_w, up_bf,  NE * NH * ND / 8);
        cvt_f2bf<<<dim3(2048), dim3(256), 0, stream>>>(dn_w, dn_bf,  NE * ND * NH / 8);
        cvt_f2bf<<<dim3(1024), dim3(256), 0, stream>>>(sup,  sup_bf, NHS * ND / 8);
        cvt_f2bf<<<dim3(1024), dim3(256), 0, stream>>>(sdn,  sdn_bf, ND * NHS / 8);

        moe_gemm_bf<0><<<dim3(NH / 128, CAPE / 128, NE), dim3(256), 0, stream>>>(
            Xbf, up_bf, cnt, tok_list, w_list, Hbuf, nullptr);
        moe_gemm_bf<2><<<dim3(NHS / 128, NT / 128, 1), dim3(256), 0, stream>>>(
            Xbf, sup_bf, nullptr, nullptr, nullptr, Sbuf, nullptr);
        moe_gemm_bf<3><<<dim3(ND / 128, NT / 128, 1), dim3(256), 0, stream>>>(
            Sbuf, sdn_bf, nullptr, nullptr, nullptr, nullptr, out);
        moe_gemm_bf<1><<<dim3(ND / 128, CAPE / 128, NE), dim3(256), 0, stream>>>(
            Hbuf, dn_bf, cnt, tok_list, w_list, nullptr, out);
    } else {
        moe_gemm_f32<0><<<dim3(NH / 128, CAPE / 128, NE), dim3(256), 0, stream>>>(
            X, nullptr, up_w, cnt, tok_list, w_list, Hbuf, nullptr);
        moe_gemm_f32<2><<<dim3(NHS / 128, NT / 128, 1), dim3(256), 0, stream>>>(
            X, nullptr, sup, nullptr, nullptr, nullptr, Sbuf, nullptr);
        moe_gemm_f32<3><<<dim3(ND / 128, NT / 128, 1), dim3(256), 0, stream>>>(
            nullptr, Sbuf, sdn, nullptr, nullptr, nullptr, nullptr, out);
        moe_gemm_f32<1><<<dim3(ND / 128, CAPE / 128, NE), dim3(256), 0, stream>>>(
            nullptr, Hbuf, dn_w, cnt, tok_list, w_list, nullptr, out);
    }
}

// Round 3
// 811.190 us; speedup vs baseline: 1.1711x; 1.0349x over previous
//
#include <hip/hip_runtime.h>

#define NE 32
#define NG 8
#define NK 4
#define ND 2048
#define NH 1024
#define NHS 4096
#define CAPE 1024
#define NT 4096

typedef float f32x4 __attribute__((ext_vector_type(4)));
typedef short s16x8 __attribute__((ext_vector_type(8)));

__device__ __forceinline__ short f2bf(float f) {
    return __builtin_bit_cast(short, (__bf16)f);
}
__device__ __forceinline__ float bf2f(short h) {
    return __builtin_bit_cast(float, ((unsigned)(unsigned short)h) << 16);
}

__device__ __forceinline__ void gload_lds16(const void* g, void* l) {
    __builtin_amdgcn_global_load_lds(
        (const __attribute__((address_space(1))) void*)g,
        (__attribute__((address_space(3))) void*)l, 16, 0, 0);
}

// ---------------------------------------------------------------------------
// Kernel 1: gating. One wave per token. fp32 logits, sigmoid, grouped top-k.
// ---------------------------------------------------------------------------
__global__ __launch_bounds__(256) void gate_kernel(
    const float* __restrict__ X, const float* __restrict__ Gw,
    const float* __restrict__ bias,
    int* __restrict__ topk_idx, float* __restrict__ topk_w)
{
    const int lane = threadIdx.x & 63;
    const int t = blockIdx.x * 4 + (threadIdx.x >> 6);
    const float* x = X + (size_t)t * ND;

    float xr[32];
#pragma unroll
    for (int i = 0; i < 32; i++) xr[i] = x[lane + i * 64];

    float scores[32];
#pragma unroll
    for (int e = 0; e < 32; e++) {
        const float* w = Gw + (size_t)e * ND;
        float a = 0.f;
#pragma unroll
        for (int i = 0; i < 32; i++) a = fmaf(xr[i], w[lane + i * 64], a);
#pragma unroll
        for (int s = 32; s > 0; s >>= 1) a += __shfl_xor(a, s);
        scores[e] = 1.0f / (1.0f + expf(-a));
    }

    float sc_c[32];
#pragma unroll
    for (int e = 0; e < 32; e++) sc_c[e] = scores[e] + bias[e];

    float gs[8];
#pragma unroll
    for (int g = 0; g < 8; g++) {
        float a = sc_c[4 * g], b = sc_c[4 * g + 1], c = sc_c[4 * g + 2], d = sc_c[4 * g + 3];
        float hi1 = fmaxf(a, b), lo1 = fminf(a, b);
        float hi2 = fmaxf(c, d), lo2 = fminf(c, d);
        float m1 = fmaxf(hi1, hi2);
        float m2 = fmaxf(fminf(hi1, hi2), fmaxf(lo1, lo2));
        gs[g] = m1 + m2;
    }

    unsigned gsel = 0;
#pragma unroll
    for (int it = 0; it < 4; it++) {
        int best = -1; float bv = -1e30f;
#pragma unroll
        for (int g = 0; g < 8; g++) {
            bool avail = !((gsel >> g) & 1);
            if (avail && gs[g] > bv) { bv = gs[g]; best = g; }
        }
        gsel |= 1u << best;
    }

    unsigned esel = 0;
    int idxs[4]; float wts[4];
#pragma unroll
    for (int it = 0; it < 4; it++) {
        int best = -1; float bv = -1e30f, braw = 0.f;
#pragma unroll
        for (int e = 0; e < 32; e++) {
            float mv = ((gsel >> (e >> 2)) & 1) ? sc_c[e] : 0.0f;
            bool avail = !((esel >> e) & 1);
            if (avail && mv > bv) { bv = mv; best = e; braw = scores[e]; }
        }
        esel |= 1u << best;
        idxs[it] = best; wts[it] = braw;
    }

    float s = wts[0] + wts[1] + wts[2] + wts[3] + 1e-20f;
    if (lane == 0) {
#pragma unroll
        for (int k = 0; k < 4; k++) {
            topk_idx[t * 4 + k] = idxs[k];
            topk_w[t * 4 + k] = wts[k] / s * 2.5f;
        }
    }
}

// ---------------------------------------------------------------------------
__global__ void zero_cnt(int* cnt) {
    if (threadIdx.x < NE) cnt[threadIdx.x] = 0;
}

__global__ void dispatch_kernel(const int* __restrict__ topk_idx,
                                const float* __restrict__ topk_w,
                                int* __restrict__ cnt,
                                int* __restrict__ tok_list,
                                float* __restrict__ w_list,
                                int* __restrict__ pos_list)
{
    int i = blockIdx.x * 256 + threadIdx.x;
    int e = topk_idx[i];
    int t = i >> 2;
    int pos = atomicAdd(&cnt[e], 1);
    pos_list[i] = pos;
    if (pos < CAPE) {
        tok_list[e * CAPE + pos] = t;
        w_list[e * CAPE + pos] = topk_w[i];
    }
}

// ---------------------------------------------------------------------------
// f32 -> bf16 bulk conversion (8 elems / thread / iter, grid-stride)
// ---------------------------------------------------------------------------
__global__ __launch_bounds__(256) void cvt_f2bf(const float* __restrict__ in,
                                                short* __restrict__ out, int n8)
{
    int i = blockIdx.x * 256 + threadIdx.x;
    int stride = gridDim.x * 256;
    for (; i < n8; i += stride) {
        const f32x4* p = (const f32x4*)(in + (size_t)i * 8);
        f32x4 a = p[0], b = p[1];
        s16x8 h;
        h[0] = f2bf(a[0]); h[1] = f2bf(a[1]); h[2] = f2bf(a[2]); h[3] = f2bf(a[3]);
        h[4] = f2bf(b[0]); h[5] = f2bf(b[1]); h[6] = f2bf(b[2]); h[7] = f2bf(b[3]);
        *(s16x8*)(out + (size_t)i * 8) = h;
    }
}

// ---------------------------------------------------------------------------
// Combine: out[t] = shared_down[t] (already in out) + sum_k w_k * Ybuf[e_k,pos_k]
// One block per token; each thread owns 8 consecutive channels. No atomics.
// ---------------------------------------------------------------------------
__global__ __launch_bounds__(256) void combine_kernel(
    const int* __restrict__ topk_idx, const float* __restrict__ topk_w,
    const int* __restrict__ pos_list,
    const short* __restrict__ Ybuf, float* __restrict__ out)
{
    const int t = blockIdx.x;
    const int d0 = threadIdx.x * 8;

    int e[NK], p[NK]; float w[NK];
#pragma unroll
    for (int k = 0; k < NK; k++) {
        e[k] = topk_idx[t * NK + k];
        p[k] = pos_list[t * NK + k];
        w[k] = topk_w[t * NK + k];
    }

    float* orow = out + (size_t)t * ND + d0;
    f32x4 o0 = *(f32x4*)(orow);
    f32x4 o1 = *(f32x4*)(orow + 4);

#pragma unroll
    for (int k = 0; k < NK; k++) {
        if (p[k] < CAPE) {
            s16x8 y = *(const s16x8*)(Ybuf + ((size_t)e[k] * CAPE + p[k]) * ND + d0);
            o0[0] = fmaf(w[k], bf2f(y[0]), o0[0]);
            o0[1] = fmaf(w[k], bf2f(y[1]), o0[1]);
            o0[2] = fmaf(w[k], bf2f(y[2]), o0[2]);
            o0[3] = fmaf(w[k], bf2f(y[3]), o0[3]);
            o1[0] = fmaf(w[k], bf2f(y[4]), o1[0]);
            o1[1] = fmaf(w[k], bf2f(y[5]), o1[1]);
            o1[2] = fmaf(w[k], bf2f(y[6]), o1[2]);
            o1[3] = fmaf(w[k], bf2f(y[7]), o1[3]);
        }
    }
    *(f32x4*)(orow) = o0;
    *(f32x4*)(orow + 4) = o1;
}

// ---------------------------------------------------------------------------
// GEMM (m97 structure): 128x128 tile, BK=64, global_load_lds width-16,
// 4 waves (2x2), 16x16x32 bf16 MFMA. All operands bf16 row-major [rows][K].
// MODE 0: routed up   (A = Xbf gathered,  B = up_bf[e],  out = relu2 -> Hbuf)
// MODE 1: routed down (A = Hbuf[e],       B = dn_bf[e],  out = Ybuf bf16)
// MODE 2: shared up   (A = Xbf,           B = sup_bf,    out = relu2 -> Sbuf)
// MODE 3: shared down (A = Sbuf,          B = sdn_bf,    out = f32 write)
// ---------------------------------------------------------------------------
template <int MODE>
__global__ __launch_bounds__(256) void moe_gemm_bf(
    const short* __restrict__ Abase, const short* __restrict__ Bbase,
    const int* __restrict__ cnt, const int* __restrict__ tok_list,
    short* __restrict__ Hout, float* __restrict__ out)
{
    constexpr int K = (MODE == 0) ? ND : (MODE == 1) ? NH : (MODE == 2) ? ND : NHS;

    const int e = blockIdx.z;
    const int m0 = blockIdx.y * 128, n0 = blockIdx.x * 128;

    int mcnt = 0;
    if constexpr (MODE == 0 || MODE == 1) {
        mcnt = min(cnt[e], CAPE);
        if (m0 >= mcnt) return;
    }

    __shared__ short As[128 * 64];
    __shared__ short Bs[128 * 64];

    const int tid = threadIdx.x;
    const int lane = tid & 63;
    const int wave = tid >> 6;
    const int wr = wave >> 1, wc = wave & 1;

    const short* Ab = Abase;
    const short* Bb = Bbase;
    if constexpr (MODE == 0) Bb += (size_t)e * NH * ND;
    if constexpr (MODE == 1) { Ab += (size_t)e * CAPE * NH; Bb += (size_t)e * ND * NH; }

    // per-thread staging sources (hoisted out of K-loop)
    const int rl = lane >> 3;         // row within 8-row chunk
    const int cl = (lane & 7) * 8;    // k element offset of this lane's 16B
    const short* asrc[4];
    const short* bsrc[4];
    short* adst[4];
    short* bdst[4];
#pragma unroll
    for (int i = 0; i < 4; i++) {
        int ci = i * 4 + wave;        // 1KB chunk index 0..15
        int r = ci * 8 + rl;          // tile row 0..127
        if constexpr (MODE == 0) {
            int gr = min(m0 + r, mcnt - 1);
            int tok = tok_list[e * CAPE + gr];
            asrc[i] = Abase + (size_t)tok * ND + cl;
        } else if constexpr (MODE == 1) {
            asrc[i] = Ab + (size_t)(m0 + r) * NH + cl;
        } else if constexpr (MODE == 2) {
            asrc[i] = Abase + (size_t)(m0 + r) * ND + cl;
        } else {
            asrc[i] = Abase + (size_t)(m0 + r) * NHS + cl;
        }
        bsrc[i] = Bb + (size_t)(n0 + r) * K + cl;
        adst[i] = &As[ci * 512];
        bdst[i] = &Bs[ci * 512];
    }

    f32x4 acc[4][4] = {};

    for (int k0 = 0; k0 < K; k0 += 64) {
        __syncthreads();
#pragma unroll
        for (int i = 0; i < 4; i++) {
            gload_lds16(asrc[i] + k0, adst[i]);
            gload_lds16(bsrc[i] + k0, bdst[i]);
        }
        __syncthreads();

        s16x8 af[2][4], bfr[2][4];
#pragma unroll
        for (int kk = 0; kk < 2; kk++)
#pragma unroll
            for (int i = 0; i < 4; i++) {
                af[kk][i]  = *(const s16x8*)(&As[(wr * 64 + i * 16 + (lane & 15)) * 64 + kk * 32 + (lane >> 4) * 8]);
                bfr[kk][i] = *(const s16x8*)(&Bs[(wc * 64 + i * 16 + (lane & 15)) * 64 + kk * 32 + (lane >> 4) * 8]);
            }
#pragma unroll
        for (int i = 0; i < 4; i++)
#pragma unroll
            for (int j = 0; j < 4; j++) {
                acc[i][j] = __builtin_amdgcn_mfma_f32_16x16x32_bf16(af[0][i], bfr[0][j], acc[i][j], 0, 0, 0);
                acc[i][j] = __builtin_amdgcn_mfma_f32_16x16x32_bf16(af[1][i], bfr[1][j], acc[i][j], 0, 0, 0);
            }
    }

    // ---- epilogue ----  C mapping: col = lane&15, row = (lane>>4)*4 + reg
    const int r0 = (lane >> 4) * 4;
    const int cc = lane & 15;

    if constexpr (MODE == 0 || MODE == 2) {
#pragma unroll
        for (int i = 0; i < 4; i++)
#pragma unroll
            for (int j = 0; j < 4; j++)
#pragma unroll
                for (int v = 0; v < 4; v++) {
                    int row = wr * 64 + i * 16 + r0 + v;
                    int col = wc * 64 + j * 16 + cc;
                    float val = acc[i][j][v];
                    float r = fmaxf(val, 0.f);
                    val = r * r;
                    if constexpr (MODE == 0)
                        Hout[((size_t)e * CAPE + m0 + row) * NH + (n0 + col)] = f2bf(val);
                    else
                        Hout[(size_t)(m0 + row) * NHS + (n0 + col)] = f2bf(val);
                }
    } else if constexpr (MODE == 3) {
#pragma unroll
        for (int i = 0; i < 4; i++)
#pragma unroll
            for (int j = 0; j < 4; j++)
#pragma unroll
                for (int v = 0; v < 4; v++) {
                    int row = wr * 64 + i * 16 + r0 + v;
                    int col = wc * 64 + j * 16 + cc;
                    out[(size_t)(m0 + row) * ND + (n0 + col)] = acc[i][j][v];
                }
    } else {  // MODE 1: plain bf16 store to Ybuf (valid rows only), no atomics
#pragma unroll
        for (int i = 0; i < 4; i++)
#pragma unroll
            for (int v = 0; v < 4; v++) {
                int row = wr * 64 + i * 16 + r0 + v;
                int grow = m0 + row;
                if (grow < mcnt) {
#pragma unroll
                    for (int j = 0; j < 4; j++) {
                        int col = wc * 64 + j * 16 + cc;
                        Hout[((size_t)e * CAPE + grow) * ND + (n0 + col)] = f2bf(acc[i][j][v]);
                    }
                }
            }
    }
}

// ---------------------------------------------------------------------------
extern "C" void kernel_launch(void* const* d_in, const int* in_sizes, int n_in,
                              void* d_out, int out_size, void* d_ws, size_t ws_size,
                              hipStream_t stream) {
    const float* X    = (const float*)d_in[0];
    const float* Gw   = (const float*)d_in[1];
    const float* bias = (const float*)d_in[2];
    const float* up_w = (const float*)d_in[3];
    const float* dn_w = (const float*)d_in[4];
    const float* sup  = (const float*)d_in[5];
    const float* sdn  = (const float*)d_in[6];
    float* out = (float*)d_out;

    char* ws = (char*)d_ws;
    size_t off = 0;
    auto alloc = [&](size_t bytes) -> void* {
        off = (off + 255) & ~(size_t)255;
        void* p = ws + off;
        off += bytes;
        return p;
    };
    int*   cnt      = (int*)  alloc(NE * 4);
    int*   topk_idx = (int*)  alloc((size_t)NT * NK * 4);
    float* topk_w   = (float*)alloc((size_t)NT * NK * 4);
    int*   pos_list = (int*)  alloc((size_t)NT * NK * 4);
    int*   tok_list = (int*)  alloc((size_t)NE * CAPE * 4);
    float* w_list   = (float*)alloc((size_t)NE * CAPE * 4);
    short* Hbuf     = (short*)alloc((size_t)NE * CAPE * NH * 2);   // 64 MB
    short* Sbuf     = (short*)alloc((size_t)NT * NHS * 2);         // 32 MB
    short* Xbf      = (short*)alloc((size_t)NT * ND * 2);          // 16 MB
    short* up_bf    = (short*)alloc((size_t)NE * NH * ND * 2);     // 128 MB
    short* dn_bf    = (short*)alloc((size_t)NE * ND * NH * 2);     // 128 MB
    short* sup_bf   = (short*)alloc((size_t)NHS * ND * 2);         // 16 MB
    short* sdn_bf   = (short*)alloc((size_t)ND * NHS * 2);         // 16 MB
    // Ybuf (128 MB) aliases [Xbf .. up_bf] — both dead once MODE0+MODE2 ran.
    short* Ybuf     = Xbf;

    gate_kernel<<<dim3(NT / 4), dim3(256), 0, stream>>>(X, Gw, bias, topk_idx, topk_w);
    zero_cnt<<<dim3(1), dim3(64), 0, stream>>>(cnt);
    dispatch_kernel<<<dim3(NT * NK / 256), dim3(256), 0, stream>>>(
        topk_idx, topk_w, cnt, tok_list, w_list, pos_list);

    // bulk f32 -> bf16 conversion
    cvt_f2bf<<<dim3(1024), dim3(256), 0, stream>>>(X,    Xbf,    NT * ND / 8);
    cvt_f2bf<<<dim3(2048), dim3(256), 0, stream>>>(up_w, up_bf,  NE * NH * ND / 8);
    cvt_f2bf<<<dim3(2048), dim3(256), 0, stream>>>(dn_w, dn_bf,  NE * ND * NH / 8);
    cvt_f2bf<<<dim3(1024), dim3(256), 0, stream>>>(sup,  sup_bf, NHS * ND / 8);
    cvt_f2bf<<<dim3(1024), dim3(256), 0, stream>>>(sdn,  sdn_bf, ND * NHS / 8);

    // routed up: X gathered -> Hbuf
    moe_gemm_bf<0><<<dim3(NH / 128, CAPE / 128, NE), dim3(256), 0, stream>>>(
        Xbf, up_bf, cnt, tok_list, Hbuf, nullptr);
    // shared up: X -> Sbuf
    moe_gemm_bf<2><<<dim3(NHS / 128, NT / 128, 1), dim3(256), 0, stream>>>(
        Xbf, sup_bf, nullptr, nullptr, Sbuf, nullptr);
    // shared down: Sbuf -> out (plain f32 write; MUST precede combine)
    moe_gemm_bf<3><<<dim3(ND / 128, NT / 128, 1), dim3(256), 0, stream>>>(
        Sbuf, sdn_bf, nullptr, nullptr, nullptr, out);
    // routed down: Hbuf -> Ybuf (bf16, per-slot; overwrites Xbf/up_bf region)
    moe_gemm_bf<1><<<dim3(ND / 128, CAPE / 128, NE), dim3(256), 0, stream>>>(
        Hbuf, dn_bf, cnt, tok_list, Ybuf, nullptr);
    // combine: out += sum_k w_k * Ybuf[e_k, pos_k]
    combine_kernel<<<dim3(NT), dim3(256), 0, stream>>>(
        topk_idx, topk_w, pos_list, Ybuf, out);
}

// Round 4
// 800.575 us; speedup vs baseline: 1.1866x; 1.0133x over previous
//
#include <hip/hip_runtime.h>

#define NE 32
#define NG 8
#define NK 4
#define ND 2048
#define NH 1024
#define NHS 4096
#define CAPE 1024
#define NT 4096

typedef float f32x4 __attribute__((ext_vector_type(4)));
typedef short s16x8 __attribute__((ext_vector_type(8)));

__device__ __forceinline__ short f2bf(float f) {
    return __builtin_bit_cast(short, (__bf16)f);
}
__device__ __forceinline__ float bf2f(short h) {
    return __builtin_bit_cast(float, ((unsigned)(unsigned short)h) << 16);
}

__device__ __forceinline__ void gload_lds16(const void* g, void* l) {
    __builtin_amdgcn_global_load_lds(
        (const __attribute__((address_space(1))) void*)g,
        (__attribute__((address_space(3))) void*)l, 16, 0, 0);
}

// ---------------------------------------------------------------------------
// Kernel 1: gating. One wave per token. fp32 logits, sigmoid, grouped top-k.
// ---------------------------------------------------------------------------
__global__ __launch_bounds__(256) void gate_kernel(
    const float* __restrict__ X, const float* __restrict__ Gw,
    const float* __restrict__ bias,
    int* __restrict__ topk_idx, float* __restrict__ topk_w)
{
    const int lane = threadIdx.x & 63;
    const int t = blockIdx.x * 4 + (threadIdx.x >> 6);
    const float* x = X + (size_t)t * ND;

    float xr[32];
#pragma unroll
    for (int i = 0; i < 32; i++) xr[i] = x[lane + i * 64];

    float scores[32];
#pragma unroll
    for (int e = 0; e < 32; e++) {
        const float* w = Gw + (size_t)e * ND;
        float a = 0.f;
#pragma unroll
        for (int i = 0; i < 32; i++) a = fmaf(xr[i], w[lane + i * 64], a);
#pragma unroll
        for (int s = 32; s > 0; s >>= 1) a += __shfl_xor(a, s);
        scores[e] = 1.0f / (1.0f + expf(-a));
    }

    float sc_c[32];
#pragma unroll
    for (int e = 0; e < 32; e++) sc_c[e] = scores[e] + bias[e];

    float gs[8];
#pragma unroll
    for (int g = 0; g < 8; g++) {
        float a = sc_c[4 * g], b = sc_c[4 * g + 1], c = sc_c[4 * g + 2], d = sc_c[4 * g + 3];
        float hi1 = fmaxf(a, b), lo1 = fminf(a, b);
        float hi2 = fmaxf(c, d), lo2 = fminf(c, d);
        float m1 = fmaxf(hi1, hi2);
        float m2 = fmaxf(fminf(hi1, hi2), fmaxf(lo1, lo2));
        gs[g] = m1 + m2;
    }

    unsigned gsel = 0;
#pragma unroll
    for (int it = 0; it < 4; it++) {
        int best = -1; float bv = -1e30f;
#pragma unroll
        for (int g = 0; g < 8; g++) {
            bool avail = !((gsel >> g) & 1);
            if (avail && gs[g] > bv) { bv = gs[g]; best = g; }
        }
        gsel |= 1u << best;
    }

    unsigned esel = 0;
    int idxs[4]; float wts[4];
#pragma unroll
    for (int it = 0; it < 4; it++) {
        int best = -1; float bv = -1e30f, braw = 0.f;
#pragma unroll
        for (int e = 0; e < 32; e++) {
            float mv = ((gsel >> (e >> 2)) & 1) ? sc_c[e] : 0.0f;
            bool avail = !((esel >> e) & 1);
            if (avail && mv > bv) { bv = mv; best = e; braw = scores[e]; }
        }
        esel |= 1u << best;
        idxs[it] = best; wts[it] = braw;
    }

    float s = wts[0] + wts[1] + wts[2] + wts[3] + 1e-20f;
    if (lane == 0) {
#pragma unroll
        for (int k = 0; k < 4; k++) {
            topk_idx[t * 4 + k] = idxs[k];
            topk_w[t * 4 + k] = wts[k] / s * 2.5f;
        }
    }
}

// ---------------------------------------------------------------------------
__global__ void zero_cnt(int* cnt) {
    if (threadIdx.x < NE) cnt[threadIdx.x] = 0;
}

__global__ void dispatch_kernel(const int* __restrict__ topk_idx,
                                const float* __restrict__ topk_w,
                                int* __restrict__ cnt,
                                int* __restrict__ tok_list,
                                float* __restrict__ w_list,
                                int* __restrict__ pos_list)
{
    int i = blockIdx.x * 256 + threadIdx.x;
    int e = topk_idx[i];
    int t = i >> 2;
    int pos = atomicAdd(&cnt[e], 1);
    pos_list[i] = pos;
    if (pos < CAPE) {
        tok_list[e * CAPE + pos] = t;
        w_list[e * CAPE + pos] = topk_w[i];
    }
}

// ---------------------------------------------------------------------------
// f32 -> bf16 bulk conversion (8 elems / thread / iter, grid-stride)
// ---------------------------------------------------------------------------
__global__ __launch_bounds__(256) void cvt_f2bf(const float* __restrict__ in,
                                                short* __restrict__ out, int n8)
{
    int i = blockIdx.x * 256 + threadIdx.x;
    int stride = gridDim.x * 256;
    for (; i < n8; i += stride) {
        const f32x4* p = (const f32x4*)(in + (size_t)i * 8);
        f32x4 a = p[0], b = p[1];
        s16x8 h;
        h[0] = f2bf(a[0]); h[1] = f2bf(a[1]); h[2] = f2bf(a[2]); h[3] = f2bf(a[3]);
        h[4] = f2bf(b[0]); h[5] = f2bf(b[1]); h[6] = f2bf(b[2]); h[7] = f2bf(b[3]);
        *(s16x8*)(out + (size_t)i * 8) = h;
    }
}

// ---------------------------------------------------------------------------
// Combine: out[t] = shared_down[t] (already in out) + sum_k w_k * Ybuf[e_k,pos_k]
// ---------------------------------------------------------------------------
__global__ __launch_bounds__(256) void combine_kernel(
    const int* __restrict__ topk_idx, const float* __restrict__ topk_w,
    const int* __restrict__ pos_list,
    const short* __restrict__ Ybuf, float* __restrict__ out)
{
    const int t = blockIdx.x;
    const int d0 = threadIdx.x * 8;

    int e[NK], p[NK]; float w[NK];
#pragma unroll
    for (int k = 0; k < NK; k++) {
        e[k] = topk_idx[t * NK + k];
        p[k] = pos_list[t * NK + k];
        w[k] = topk_w[t * NK + k];
    }

    float* orow = out + (size_t)t * ND + d0;
    f32x4 o0 = *(f32x4*)(orow);
    f32x4 o1 = *(f32x4*)(orow + 4);

#pragma unroll
    for (int k = 0; k < NK; k++) {
        if (p[k] < CAPE) {
            s16x8 y = *(const s16x8*)(Ybuf + ((size_t)e[k] * CAPE + p[k]) * ND + d0);
            o0[0] = fmaf(w[k], bf2f(y[0]), o0[0]);
            o0[1] = fmaf(w[k], bf2f(y[1]), o0[1]);
            o0[2] = fmaf(w[k], bf2f(y[2]), o0[2]);
            o0[3] = fmaf(w[k], bf2f(y[3]), o0[3]);
            o1[0] = fmaf(w[k], bf2f(y[4]), o1[0]);
            o1[1] = fmaf(w[k], bf2f(y[5]), o1[1]);
            o1[2] = fmaf(w[k], bf2f(y[6]), o1[2]);
            o1[3] = fmaf(w[k], bf2f(y[7]), o1[3]);
        }
    }
    *(f32x4*)(orow) = o0;
    *(f32x4*)(orow + 4) = o1;
}

// ---------------------------------------------------------------------------
// GEMM: 128x128 tile, BK=32, DOUBLE-BUFFERED LDS (2x16KB), prefetch-before-
// compute (T3 minimum-2-phase), both-sides XOR swizzle (rule #21):
//   staging: linear gload_lds dest; lane's GLOBAL col = ((l&3)^((l>>3)&3))*8
//   reading: phys 16B slot = (lane>>4) ^ ((lane>>1)&3)
// 4 waves (2x2), 16x16x32 bf16 MFMA, 4x4 frags/wave.
// MODE 0: routed up   (A = Xbf gathered,  B = up_bf[e],  out = relu2 -> Hbuf)
// MODE 1: routed down (A = Hbuf[e],       B = dn_bf[e],  out = Ybuf bf16)
// MODE 2: shared up   (A = Xbf,           B = sup_bf,    out = relu2 -> Sbuf)
// MODE 3: shared down (A = Sbuf,          B = sdn_bf,    out = f32 write)
// ---------------------------------------------------------------------------
template <int MODE>
__global__ __launch_bounds__(256) void moe_gemm_bf(
    const short* __restrict__ Abase, const short* __restrict__ Bbase,
    const int* __restrict__ cnt, const int* __restrict__ tok_list,
    short* __restrict__ Hout, float* __restrict__ out)
{
    constexpr int K = (MODE == 0) ? ND : (MODE == 1) ? NH : (MODE == 2) ? ND : NHS;
    constexpr int NITER = K / 32;

    const int e = blockIdx.z;
    const int m0 = blockIdx.y * 128, n0 = blockIdx.x * 128;

    int mcnt = 0;
    if constexpr (MODE == 0 || MODE == 1) {
        mcnt = min(cnt[e], CAPE);
        if (m0 >= mcnt) return;
    }

    __shared__ short As[2][128 * 32];
    __shared__ short Bs[2][128 * 32];

    const int tid = threadIdx.x;
    const int lane = tid & 63;
    const int wave = tid >> 6;
    const int wr = wave >> 1, wc = wave & 1;

    const short* Ab = Abase;
    const short* Bb = Bbase;
    if constexpr (MODE == 0) Bb += (size_t)e * NH * ND;
    if constexpr (MODE == 1) { Ab += (size_t)e * CAPE * NH; Bb += (size_t)e * ND * NH; }

    // staging geometry: 8 chunks of 1 KB each for A and B (chunk = 16 rows x 32 elems)
    // lane l -> dest row ci*16 + (l>>2), phys slot l&3 (linear, HW lane*16B);
    // inverse-swizzled global col so that read-side swizzle sees logical data.
    const int srow = lane >> 2;
    const int scol = ((lane & 3) ^ ((lane >> 3) & 3)) * 8;
    const short* asrc[2];
    const short* bsrc[2];
    int dstchunk[2];
#pragma unroll
    for (int i = 0; i < 2; i++) {
        int ci = i * 4 + wave;           // chunk 0..7
        int r = ci * 16 + srow;          // tile row 0..127
        if constexpr (MODE == 0) {
            int gr = min(m0 + r, mcnt - 1);
            int tok = tok_list[e * CAPE + gr];
            asrc[i] = Abase + (size_t)tok * ND + scol;
        } else if constexpr (MODE == 1) {
            asrc[i] = Ab + (size_t)(m0 + r) * NH + scol;
        } else if constexpr (MODE == 2) {
            asrc[i] = Abase + (size_t)(m0 + r) * ND + scol;
        } else {
            asrc[i] = Abase + (size_t)(m0 + r) * NHS + scol;
        }
        bsrc[i] = Bb + (size_t)(n0 + r) * K + scol;
        dstchunk[i] = ci * 512;          // wave-uniform chunk base (elems)
    }

    // frag-read addressing (swizzled)
    const int fr = lane & 15;
    const int fcol = ((lane >> 4) ^ ((lane >> 1) & 3)) * 8;

    f32x4 acc[4][4] = {};

    // prologue: stage K-tile 0 into buffer 0
#pragma unroll
    for (int i = 0; i < 2; i++) {
        gload_lds16(asrc[i], &As[0][dstchunk[i]]);
        gload_lds16(bsrc[i], &Bs[0][dstchunk[i]]);
    }

    int buf = 0;
    for (int it = 0; it < NITER; ++it) {
        __syncthreads();   // implicit vmcnt(0): stage of `buf` complete; prev reads done
        if (it + 1 < NITER) {
            const int ko = (it + 1) * 32;
#pragma unroll
            for (int i = 0; i < 2; i++) {
                gload_lds16(asrc[i] + ko, &As[buf ^ 1][dstchunk[i]]);
                gload_lds16(bsrc[i] + ko, &Bs[buf ^ 1][dstchunk[i]]);
            }
        }
        s16x8 af[4], bfr[4];
#pragma unroll
        for (int i = 0; i < 4; i++) {
            af[i]  = *(const s16x8*)(&As[buf][(wr * 64 + i * 16 + fr) * 32 + fcol]);
            bfr[i] = *(const s16x8*)(&Bs[buf][(wc * 64 + i * 16 + fr) * 32 + fcol]);
        }
#pragma unroll
        for (int i = 0; i < 4; i++)
#pragma unroll
            for (int j = 0; j < 4; j++)
                acc[i][j] = __builtin_amdgcn_mfma_f32_16x16x32_bf16(af[i], bfr[j], acc[i][j], 0, 0, 0);
        buf ^= 1;
    }

    // ---- epilogue ----  C mapping: col = lane&15, row = (lane>>4)*4 + reg
    const int r0 = (lane >> 4) * 4;
    const int cc = lane & 15;

    if constexpr (MODE == 0 || MODE == 2) {
#pragma unroll
        for (int i = 0; i < 4; i++)
#pragma unroll
            for (int j = 0; j < 4; j++)
#pragma unroll
                for (int v = 0; v < 4; v++) {
                    int row = wr * 64 + i * 16 + r0 + v;
                    int col = wc * 64 + j * 16 + cc;
                    float val = acc[i][j][v];
                    float r = fmaxf(val, 0.f);
                    val = r * r;
                    if constexpr (MODE == 0)
                        Hout[((size_t)e * CAPE + m0 + row) * NH + (n0 + col)] = f2bf(val);
                    else
                        Hout[(size_t)(m0 + row) * NHS + (n0 + col)] = f2bf(val);
                }
    } else if constexpr (MODE == 3) {
#pragma unroll
        for (int i = 0; i < 4; i++)
#pragma unroll
            for (int j = 0; j < 4; j++)
#pragma unroll
                for (int v = 0; v < 4; v++) {
                    int row = wr * 64 + i * 16 + r0 + v;
                    int col = wc * 64 + j * 16 + cc;
                    out[(size_t)(m0 + row) * ND + (n0 + col)] = acc[i][j][v];
                }
    } else {  // MODE 1: plain bf16 store to Ybuf (valid rows only)
#pragma unroll
        for (int i = 0; i < 4; i++)
#pragma unroll
            for (int v = 0; v < 4; v++) {
                int row = wr * 64 + i * 16 + r0 + v;
                int grow = m0 + row;
                if (grow < mcnt) {
#pragma unroll
                    for (int j = 0; j < 4; j++) {
                        int col = wc * 64 + j * 16 + cc;
                        Hout[((size_t)e * CAPE + grow) * ND + (n0 + col)] = f2bf(acc[i][j][v]);
                    }
                }
            }
    }
}

// ---------------------------------------------------------------------------
extern "C" void kernel_launch(void* const* d_in, const int* in_sizes, int n_in,
                              void* d_out, int out_size, void* d_ws, size_t ws_size,
                              hipStream_t stream) {
    const float* X    = (const float*)d_in[0];
    const float* Gw   = (const float*)d_in[1];
    const float* bias = (const float*)d_in[2];
    const float* up_w = (const float*)d_in[3];
    const float* dn_w = (const float*)d_in[4];
    const float* sup  = (const float*)d_in[5];
    const float* sdn  = (const float*)d_in[6];
    float* out = (float*)d_out;

    char* ws = (char*)d_ws;
    size_t off = 0;
    auto alloc = [&](size_t bytes) -> void* {
        off = (off + 255) & ~(size_t)255;
        void* p = ws + off;
        off += bytes;
        return p;
    };
    int*   cnt      = (int*)  alloc(NE * 4);
    int*   topk_idx = (int*)  alloc((size_t)NT * NK * 4);
    float* topk_w   = (float*)alloc((size_t)NT * NK * 4);
    int*   pos_list = (int*)  alloc((size_t)NT * NK * 4);
    int*   tok_list = (int*)  alloc((size_t)NE * CAPE * 4);
    float* w_list   = (float*)alloc((size_t)NE * CAPE * 4);
    short* Hbuf     = (short*)alloc((size_t)NE * CAPE * NH * 2);   // 64 MB
    short* Sbuf     = (short*)alloc((size_t)NT * NHS * 2);         // 32 MB
    short* Xbf      = (short*)alloc((size_t)NT * ND * 2);          // 16 MB
    short* up_bf    = (short*)alloc((size_t)NE * NH * ND * 2);     // 128 MB
    short* dn_bf    = (short*)alloc((size_t)NE * ND * NH * 2);     // 128 MB
    short* sup_bf   = (short*)alloc((size_t)NHS * ND * 2);         // 16 MB
    short* sdn_bf   = (short*)alloc((size_t)ND * NHS * 2);         // 16 MB
    // Ybuf (128 MB) aliases [Xbf .. up_bf] — both dead once MODE0+MODE2 ran.
    short* Ybuf     = Xbf;

    gate_kernel<<<dim3(NT / 4), dim3(256), 0, stream>>>(X, Gw, bias, topk_idx, topk_w);
    zero_cnt<<<dim3(1), dim3(64), 0, stream>>>(cnt);
    dispatch_kernel<<<dim3(NT * NK / 256), dim3(256), 0, stream>>>(
        topk_idx, topk_w, cnt, tok_list, w_list, pos_list);

    // bulk f32 -> bf16 conversion
    cvt_f2bf<<<dim3(1024), dim3(256), 0, stream>>>(X,    Xbf,    NT * ND / 8);
    cvt_f2bf<<<dim3(2048), dim3(256), 0, stream>>>(up_w, up_bf,  NE * NH * ND / 8);
    cvt_f2bf<<<dim3(2048), dim3(256), 0, stream>>>(dn_w, dn_bf,  NE * ND * NH / 8);
    cvt_f2bf<<<dim3(1024), dim3(256), 0, stream>>>(sup,  sup_bf, NHS * ND / 8);
    cvt_f2bf<<<dim3(1024), dim3(256), 0, stream>>>(sdn,  sdn_bf, ND * NHS / 8);

    // routed up: X gathered -> Hbuf
    moe_gemm_bf<0><<<dim3(NH / 128, CAPE / 128, NE), dim3(256), 0, stream>>>(
        Xbf, up_bf, cnt, tok_list, Hbuf, nullptr);
    // shared up: X -> Sbuf
    moe_gemm_bf<2><<<dim3(NHS / 128, NT / 128, 1), dim3(256), 0, stream>>>(
        Xbf, sup_bf, nullptr, nullptr, Sbuf, nullptr);
    // shared down: Sbuf -> out (plain f32 write; MUST precede combine)
    moe_gemm_bf<3><<<dim3(ND / 128, NT / 128, 1), dim3(256), 0, stream>>>(
        Sbuf, sdn_bf, nullptr, nullptr, nullptr, out);
    // routed down: Hbuf -> Ybuf (bf16, per-slot; overwrites Xbf/up_bf region)
    moe_gemm_bf<1><<<dim3(ND / 128, CAPE / 128, NE), dim3(256), 0, stream>>>(
        Hbuf, dn_bf, cnt, tok_list, Ybuf, nullptr);
    // combine: out += sum_k w_k * Ybuf[e_k, pos_k]
    combine_kernel<<<dim3(NT), dim3(256), 0, stream>>>(
        topk_idx, topk_w, pos_list, Ybuf, out);
}

// Round 6
// 779.605 us; speedup vs baseline: 1.2185x; 1.0269x over previous
//
#include <hip/hip_runtime.h>

#define NE 32
#define NG 8
#define NK 4
#define ND 2048
#define NH 1024
#define NHS 4096
#define CAPE 1024
#define NT 4096

typedef float f32x4 __attribute__((ext_vector_type(4)));
typedef short s16x8 __attribute__((ext_vector_type(8)));

__device__ __forceinline__ short f2bf(float f) {
    return __builtin_bit_cast(short, (__bf16)f);
}
__device__ __forceinline__ float bf2f(short h) {
    return __builtin_bit_cast(float, ((unsigned)(unsigned short)h) << 16);
}

__device__ __forceinline__ void gload_lds16(const void* g, void* l) {
    __builtin_amdgcn_global_load_lds(
        (const __attribute__((address_space(1))) void*)g,
        (__attribute__((address_space(3))) void*)l, 16, 0, 0);
}

// ---------------------------------------------------------------------------
// Kernel 1: gating. One wave per token. fp32 logits, sigmoid, grouped top-k.
// ---------------------------------------------------------------------------
__global__ __launch_bounds__(256) void gate_kernel(
    const float* __restrict__ X, const float* __restrict__ Gw,
    const float* __restrict__ bias,
    int* __restrict__ topk_idx, float* __restrict__ topk_w)
{
    const int lane = threadIdx.x & 63;
    const int t = blockIdx.x * 4 + (threadIdx.x >> 6);
    const float* x = X + (size_t)t * ND;

    float xr[32];
#pragma unroll
    for (int i = 0; i < 32; i++) xr[i] = x[lane + i * 64];

    float scores[32];
#pragma unroll
    for (int e = 0; e < 32; e++) {
        const float* w = Gw + (size_t)e * ND;
        float a = 0.f;
#pragma unroll
        for (int i = 0; i < 32; i++) a = fmaf(xr[i], w[lane + i * 64], a);
#pragma unroll
        for (int s = 32; s > 0; s >>= 1) a += __shfl_xor(a, s);
        scores[e] = 1.0f / (1.0f + expf(-a));
    }

    float sc_c[32];
#pragma unroll
    for (int e = 0; e < 32; e++) sc_c[e] = scores[e] + bias[e];

    float gs[8];
#pragma unroll
    for (int g = 0; g < 8; g++) {
        float a = sc_c[4 * g], b = sc_c[4 * g + 1], c = sc_c[4 * g + 2], d = sc_c[4 * g + 3];
        float hi1 = fmaxf(a, b), lo1 = fminf(a, b);
        float hi2 = fmaxf(c, d), lo2 = fminf(c, d);
        float m1 = fmaxf(hi1, hi2);
        float m2 = fmaxf(fminf(hi1, hi2), fmaxf(lo1, lo2));
        gs[g] = m1 + m2;
    }

    unsigned gsel = 0;
#pragma unroll
    for (int it = 0; it < 4; it++) {
        int best = -1; float bv = -1e30f;
#pragma unroll
        for (int g = 0; g < 8; g++) {
            bool avail = !((gsel >> g) & 1);
            if (avail && gs[g] > bv) { bv = gs[g]; best = g; }
        }
        gsel |= 1u << best;
    }

    unsigned esel = 0;
    int idxs[4]; float wts[4];
#pragma unroll
    for (int it = 0; it < 4; it++) {
        int best = -1; float bv = -1e30f, braw = 0.f;
#pragma unroll
        for (int e = 0; e < 32; e++) {
            float mv = ((gsel >> (e >> 2)) & 1) ? sc_c[e] : 0.0f;
            bool avail = !((esel >> e) & 1);
            if (avail && mv > bv) { bv = mv; best = e; braw = scores[e]; }
        }
        esel |= 1u << best;
        idxs[it] = best; wts[it] = braw;
    }

    float s = wts[0] + wts[1] + wts[2] + wts[3] + 1e-20f;
    if (lane == 0) {
#pragma unroll
        for (int k = 0; k < 4; k++) {
            topk_idx[t * 4 + k] = idxs[k];
            topk_w[t * 4 + k] = wts[k] / s * 2.5f;
        }
    }
}

// ---------------------------------------------------------------------------
__global__ void zero_cnt(int* cnt) {
    if (threadIdx.x < NE) cnt[threadIdx.x] = 0;
}

__global__ void dispatch_kernel(const int* __restrict__ topk_idx,
                                int* __restrict__ cnt,
                                int* __restrict__ tok_list,
                                int* __restrict__ pos_list)
{
    int i = blockIdx.x * 256 + threadIdx.x;
    int e = topk_idx[i];
    int t = i >> 2;
    int pos = atomicAdd(&cnt[e], 1);
    pos_list[i] = pos;
    if (pos < CAPE) {
        tok_list[e * CAPE + pos] = t;
    }
}

// ---------------------------------------------------------------------------
// f32 -> bf16 bulk conversion (8 elems / thread / iter, grid-stride)
// ---------------------------------------------------------------------------
__global__ __launch_bounds__(256) void cvt_f2bf(const float* __restrict__ in,
                                                short* __restrict__ out, int n8)
{
    int i = blockIdx.x * 256 + threadIdx.x;
    int stride = gridDim.x * 256;
    for (; i < n8; i += stride) {
        const f32x4* p = (const f32x4*)(in + (size_t)i * 8);
        f32x4 a = p[0], b = p[1];
        s16x8 h;
        h[0] = f2bf(a[0]); h[1] = f2bf(a[1]); h[2] = f2bf(a[2]); h[3] = f2bf(a[3]);
        h[4] = f2bf(b[0]); h[5] = f2bf(b[1]); h[6] = f2bf(b[2]); h[7] = f2bf(b[3]);
        *(s16x8*)(out + (size_t)i * 8) = h;
    }
}

// ---------------------------------------------------------------------------
// Combine: out[t] = shared_down[t] (already in out) + sum_k w_k * Ybuf[e_k,pos_k]
// ---------------------------------------------------------------------------
__global__ __launch_bounds__(256) void combine_kernel(
    const int* __restrict__ topk_idx, const float* __restrict__ topk_w,
    const int* __restrict__ pos_list,
    const short* __restrict__ Ybuf, float* __restrict__ out)
{
    const int t = blockIdx.x;
    const int d0 = threadIdx.x * 8;

    int e[NK], p[NK]; float w[NK];
#pragma unroll
    for (int k = 0; k < NK; k++) {
        e[k] = topk_idx[t * NK + k];
        p[k] = pos_list[t * NK + k];
        w[k] = topk_w[t * NK + k];
    }

    float* orow = out + (size_t)t * ND + d0;
    f32x4 o0 = *(f32x4*)(orow);
    f32x4 o1 = *(f32x4*)(orow + 4);

#pragma unroll
    for (int k = 0; k < NK; k++) {
        if (p[k] < CAPE) {
            s16x8 y = *(const s16x8*)(Ybuf + ((size_t)e[k] * CAPE + p[k]) * ND + d0);
            o0[0] = fmaf(w[k], bf2f(y[0]), o0[0]);
            o0[1] = fmaf(w[k], bf2f(y[1]), o0[1]);
            o0[2] = fmaf(w[k], bf2f(y[2]), o0[2]);
            o0[3] = fmaf(w[k], bf2f(y[3]), o0[3]);
            o1[0] = fmaf(w[k], bf2f(y[4]), o1[0]);
            o1[1] = fmaf(w[k], bf2f(y[5]), o1[1]);
            o1[2] = fmaf(w[k], bf2f(y[6]), o1[2]);
            o1[3] = fmaf(w[k], bf2f(y[7]), o1[3]);
        }
    }
    *(f32x4*)(orow) = o0;
    *(f32x4*)(orow + 4) = o1;
}

// ---------------------------------------------------------------------------
// 8-wave GEMM: 256x256 tile, BK=64, 8 waves (2Mx4N, wave tile 128x64),
// LDS 128 KB double-buffer, counted vmcnt(8) across raw barriers, setprio
// around MFMA clusters, both-sides XOR swizzle (phys slot = slot ^ (row&7)).
// Per K-tile: 2 phases of {12x ds_read_b128, lgkmcnt(0), 32 MFMA}; staging of
// tile t+2 issued after the phase-B barrier (all waves done reading buf).
// MODE 0: routed up   (A = Xbf gathered,  B = up_bf[e],  out = relu2 -> Hbuf)
// MODE 1: routed down (A = Hbuf[e],       B = dn_bf[e],  out = Ybuf bf16)
// MODE 2: shared up   (A = Xbf,           B = sup_bf,    out = relu2 -> Sbuf)
// MODE 3: shared down (A = Sbuf,          B = sdn_bf,    out = f32 write)
// ---------------------------------------------------------------------------
template <int MODE>
__global__ __launch_bounds__(512, 2) void moe_gemm8(
    const short* __restrict__ Abase, const short* __restrict__ Bbase,
    const int* __restrict__ cnt, const int* __restrict__ tok_list,
    short* __restrict__ Hout, float* __restrict__ out)
{
    constexpr int K = (MODE == 0) ? ND : (MODE == 1) ? NH : (MODE == 2) ? ND : NHS;
    constexpr int NTILES = K / 64;

    const int e = blockIdx.z;
    const int m0 = blockIdx.y * 256, n0 = blockIdx.x * 256;

    int mcnt = 0;
    if constexpr (MODE == 0 || MODE == 1) {
        mcnt = min(cnt[e], CAPE);
        if (m0 >= mcnt) return;
    }

    __shared__ short As[2][256 * 64];
    __shared__ short Bs[2][256 * 64];

    const int tid = threadIdx.x;
    const int lane = tid & 63;
    const int wave = tid >> 6;
    const int wrM = wave >> 2;   // 0..1 -> rows wrM*128..+127
    const int wrN = wave & 3;    // 0..3 -> cols wrN*64..+63

    const short* Ab = Abase;
    const short* Bb = Bbase;
    if constexpr (MODE == 0) Bb += (size_t)e * NH * ND;
    if constexpr (MODE == 1) { Ab += (size_t)e * CAPE * NH; Bb += (size_t)e * ND * NH; }

    // ---- staging geometry: 4 ops x (A,B); op o covers rows o*64..o*64+63 ----
    // thread: row-in-chunk = tid>>3, phys slot p = tid&7 (linear lane*16B dest);
    // global col inverse-swizzled so read-side swizzle recovers logical slots.
    const int srow = tid >> 3;                 // 0..63
    const int p = tid & 7;
    const int gcol = (p ^ (srow & 7)) * 8;
    const short* asrc[4];
    const short* bsrc[4];
    int dstoff[4];                              // wave-uniform element offsets
#pragma unroll
    for (int o = 0; o < 4; o++) {
        int r = o * 64 + srow;                  // tile row 0..255
        if constexpr (MODE == 0) {
            int gr = min(m0 + r, mcnt - 1);
            int tok = tok_list[e * CAPE + gr];
            asrc[o] = Abase + (size_t)tok * ND + gcol;
        } else if constexpr (MODE == 1) {
            int gr = min(m0 + r, mcnt - 1);
            asrc[o] = Ab + (size_t)gr * NH + gcol;
        } else if constexpr (MODE == 2) {
            asrc[o] = Abase + (size_t)(m0 + r) * ND + gcol;
        } else {
            asrc[o] = Abase + (size_t)(m0 + r) * NHS + gcol;
        }
        bsrc[o] = Bb + (size_t)(n0 + r) * K + gcol;
        dstoff[o] = o * 4096 + wave * 512;
    }

    auto STAGE = [&](int tt) {
        const int ko = (tt < NTILES ? tt : NTILES - 1) * 64;
        short* Ad = As[tt & 1];
        short* Bd = Bs[tt & 1];
#pragma unroll
        for (int o = 0; o < 4; o++) {
            gload_lds16(asrc[o] + ko, Ad + dstoff[o]);
            gload_lds16(bsrc[o] + ko, Bd + dstoff[o]);
        }
    };

    // ---- fragment read offsets (kh=0; kh=1 = off ^ 32) ----
    const int r16 = lane & 15, hi4 = lane >> 4, lo3 = lane & 7;
    const int physbase = (hi4 ^ lo3) * 8;
    int offA[8], offB[4];
#pragma unroll
    for (int m = 0; m < 8; m++)
        offA[m] = (wrM * 128 + m * 16 + r16) * 64 + physbase;
#pragma unroll
    for (int n = 0; n < 4; n++)
        offB[n] = (wrN * 64 + n * 16 + r16) * 64 + physbase;

    f32x4 acc[8][4] = {};

    STAGE(0);
    STAGE(1);

    for (int t = 0; t < NTILES; ++t) {
        const short* At = As[t & 1];
        const short* Bt = Bs[t & 1];
        // tile t's 8 loads (oldest) complete; tile t+1's 8 stay in flight
        asm volatile("s_waitcnt vmcnt(8)" ::: "memory");
        __builtin_amdgcn_s_barrier();
        __builtin_amdgcn_sched_barrier(0);
        // ---- phase A: k-half 0 ----
        s16x8 af[8], bf[4];
#pragma unroll
        for (int m = 0; m < 8; m++) af[m] = *(const s16x8*)(At + offA[m]);
#pragma unroll
        for (int n = 0; n < 4; n++) bf[n] = *(const s16x8*)(Bt + offB[n]);
        asm volatile("s_waitcnt lgkmcnt(0)" ::: "memory");
        __builtin_amdgcn_sched_barrier(0);
        __builtin_amdgcn_s_setprio(1);
#pragma unroll
        for (int m = 0; m < 8; m++)
#pragma unroll
            for (int n = 0; n < 4; n++)
                acc[m][n] = __builtin_amdgcn_mfma_f32_16x16x32_bf16(af[m], bf[n], acc[m][n], 0, 0, 0);
        __builtin_amdgcn_s_setprio(0);
        // ---- phase B: k-half 1 ----
        s16x8 ag[8], bg[4];
#pragma unroll
        for (int m = 0; m < 8; m++) ag[m] = *(const s16x8*)(At + (offA[m] ^ 32));
#pragma unroll
        for (int n = 0; n < 4; n++) bg[n] = *(const s16x8*)(Bt + (offB[n] ^ 32));
        asm volatile("s_waitcnt lgkmcnt(0)" ::: "memory");
        __builtin_amdgcn_sched_barrier(0);
        __builtin_amdgcn_s_barrier();        // all waves done reading buf[t&1]
        __builtin_amdgcn_sched_barrier(0);
        STAGE(t + 2);                        // safe: lands after all reads retired
        __builtin_amdgcn_s_setprio(1);
#pragma unroll
        for (int m = 0; m < 8; m++)
#pragma unroll
            for (int n = 0; n < 4; n++)
                acc[m][n] = __builtin_amdgcn_mfma_f32_16x16x32_bf16(ag[m], bg[n], acc[m][n], 0, 0, 0);
        __builtin_amdgcn_s_setprio(0);
    }

    // ---- epilogue ----  C mapping: col = lane&15, row = (lane>>4)*4 + reg
    const int r0 = (lane >> 4) * 4;
    const int cc = lane & 15;

    if constexpr (MODE == 0 || MODE == 2) {
#pragma unroll
        for (int i = 0; i < 8; i++)
#pragma unroll
            for (int j = 0; j < 4; j++)
#pragma unroll
                for (int v = 0; v < 4; v++) {
                    int row = wrM * 128 + i * 16 + r0 + v;
                    int col = wrN * 64 + j * 16 + cc;
                    float val = acc[i][j][v];
                    float r = fmaxf(val, 0.f);
                    val = r * r;
                    if constexpr (MODE == 0)
                        Hout[((size_t)e * CAPE + m0 + row) * NH + (n0 + col)] = f2bf(val);
                    else
                        Hout[(size_t)(m0 + row) * NHS + (n0 + col)] = f2bf(val);
                }
    } else if constexpr (MODE == 3) {
#pragma unroll
        for (int i = 0; i < 8; i++)
#pragma unroll
            for (int j = 0; j < 4; j++)
#pragma unroll
                for (int v = 0; v < 4; v++) {
                    int row = wrM * 128 + i * 16 + r0 + v;
                    int col = wrN * 64 + j * 16 + cc;
                    out[(size_t)(m0 + row) * ND + (n0 + col)] = acc[i][j][v];
                }
    } else {  // MODE 1: bf16 store to Ybuf, valid rows only
#pragma unroll
        for (int i = 0; i < 8; i++)
#pragma unroll
            for (int v = 0; v < 4; v++) {
                int row = wrM * 128 + i * 16 + r0 + v;
                int grow = m0 + row;
                if (grow < mcnt) {
#pragma unroll
                    for (int j = 0; j < 4; j++) {
                        int col = wrN * 64 + j * 16 + cc;
                        Hout[((size_t)e * CAPE + grow) * ND + (n0 + col)] = f2bf(acc[i][j][v]);
                    }
                }
            }
    }
}

// ---------------------------------------------------------------------------
extern "C" void kernel_launch(void* const* d_in, const int* in_sizes, int n_in,
                              void* d_out, int out_size, void* d_ws, size_t ws_size,
                              hipStream_t stream) {
    const float* X    = (const float*)d_in[0];
    const float* Gw   = (const float*)d_in[1];
    const float* bias = (const float*)d_in[2];
    const float* up_w = (const float*)d_in[3];
    const float* dn_w = (const float*)d_in[4];
    const float* sup  = (const float*)d_in[5];
    const float* sdn  = (const float*)d_in[6];
    float* out = (float*)d_out;

    char* ws = (char*)d_ws;
    size_t off = 0;
    auto alloc = [&](size_t bytes) -> void* {
        off = (off + 255) & ~(size_t)255;
        void* p = ws + off;
        off += bytes;
        return p;
    };
    int*   cnt      = (int*)  alloc(NE * 4);
    int*   topk_idx = (int*)  alloc((size_t)NT * NK * 4);
    float* topk_w   = (float*)alloc((size_t)NT * NK * 4);
    int*   pos_list = (int*)  alloc((size_t)NT * NK * 4);
    int*   tok_list = (int*)  alloc((size_t)NE * CAPE * 4);
    short* Hbuf     = (short*)alloc((size_t)NE * CAPE * NH * 2);   // 64 MB
    short* Sbuf     = (short*)alloc((size_t)NT * NHS * 2);         // 32 MB
    short* Xbf      = (short*)alloc((size_t)NT * ND * 2);          // 16 MB
    short* up_bf    = (short*)alloc((size_t)NE * NH * ND * 2);     // 128 MB
    short* dn_bf    = (short*)alloc((size_t)NE * ND * NH * 2);     // 128 MB
    short* sup_bf   = (short*)alloc((size_t)NHS * ND * 2);         // 16 MB
    short* sdn_bf   = (short*)alloc((size_t)ND * NHS * 2);         // 16 MB
    // Ybuf (128 MB) aliases [Xbf .. up_bf] — both dead once MODE0+MODE2 ran.
    short* Ybuf     = Xbf;

    gate_kernel<<<dim3(NT / 4), dim3(256), 0, stream>>>(X, Gw, bias, topk_idx, topk_w);
    zero_cnt<<<dim3(1), dim3(64), 0, stream>>>(cnt);
    dispatch_kernel<<<dim3(NT * NK / 256), dim3(256), 0, stream>>>(
        topk_idx, cnt, tok_list, pos_list);

    // bulk f32 -> bf16 conversion
    cvt_f2bf<<<dim3(1024), dim3(256), 0, stream>>>(X,    Xbf,    NT * ND / 8);
    cvt_f2bf<<<dim3(2048), dim3(256), 0, stream>>>(up_w, up_bf,  NE * NH * ND / 8);
    cvt_f2bf<<<dim3(2048), dim3(256), 0, stream>>>(dn_w, dn_bf,  NE * ND * NH / 8);
    cvt_f2bf<<<dim3(1024), dim3(256), 0, stream>>>(sup,  sup_bf, NHS * ND / 8);
    cvt_f2bf<<<dim3(1024), dim3(256), 0, stream>>>(sdn,  sdn_bf, ND * NHS / 8);

    // routed up: X gathered -> Hbuf
    moe_gemm8<0><<<dim3(NH / 256, CAPE / 256, NE), dim3(512), 0, stream>>>(
        Xbf, up_bf, cnt, tok_list, Hbuf, nullptr);
    // shared up: X -> Sbuf
    moe_gemm8<2><<<dim3(NHS / 256, NT / 256, 1), dim3(512), 0, stream>>>(
        Xbf, sup_bf, nullptr, nullptr, Sbuf, nullptr);
    // shared down: Sbuf -> out (plain f32 write; MUST precede combine)
    moe_gemm8<3><<<dim3(ND / 256, NT / 256, 1), dim3(512), 0, stream>>>(
        Sbuf, sdn_bf, nullptr, nullptr, nullptr, out);
    // routed down: Hbuf -> Ybuf (bf16, per-slot; overwrites Xbf/up_bf region)
    moe_gemm8<1><<<dim3(ND / 256, CAPE / 256, NE), dim3(512), 0, stream>>>(
        Hbuf, dn_bf, cnt, tok_list, Ybuf, nullptr);
    // combine: out += sum_k w_k * Ybuf[e_k, pos_k]
    combine_kernel<<<dim3(NT), dim3(256), 0, stream>>>(
        topk_idx, topk_w, pos_list, Ybuf, out);
}